// Round 20
// baseline (1294.888 us; speedup 1.0000x reference)
//
#include <hip/hip_runtime.h>
#include <hip/hip_bf16.h>
#include <cstdint>

#define BQ 8
#define NQ 2048
#define FQ 128
#define NG (NQ * 16)            // adjF n-group stride in BYTES (fp8)
#define HSS 256.0f              // hs fp8 scale

typedef __attribute__((ext_vector_type(8))) short short8;
typedef __attribute__((ext_vector_type(4))) float f32x4;
typedef __attribute__((ext_vector_type(8))) unsigned short us8;
typedef __attribute__((ext_vector_type(2))) unsigned int u32x2;
typedef __attribute__((ext_vector_type(4))) unsigned int u32x4;

__device__ __forceinline__ unsigned short f2bf(float f) {
    union { float f; unsigned int u; } c; c.f = f;
    unsigned int u = c.u;
    u = (u + 0x7FFFu + ((u >> 16) & 1u)) >> 16;   // RNE
    return (unsigned short)u;
}
__device__ __forceinline__ float bf2f(unsigned short u) {
    union { unsigned int i; float f; } c; c.i = (unsigned int)u << 16; return c.f;
}
__device__ __forceinline__ unsigned int pk8lo(float a, float b, unsigned int old) {
    return (unsigned int)__builtin_amdgcn_cvt_pk_fp8_f32(a, b, (int)old, false);
}
__device__ __forceinline__ unsigned int pk8hi(float a, float b, unsigned int old) {
    return (unsigned int)__builtin_amdgcn_cvt_pk_fp8_f32(a, b, (int)old, true);
}

// Layouts (per batch):
//   xnF : bf16 [n/16][k/8][n%16][k%8]  elem addr = (n>>4)*2048 + (k>>3)*128 + (n&15)*8 + (k&7)
//   adjF: fp8  [n/16][m/8][n%16][m%8]  BYTE addr = (n>>4)*NG + (m>>3)*128 + (n&15)*8 + (m&7)
//   hsF : fp8  [m/8][f][m%8]           BYTE addr = (m>>3)*1024 + f*8 + (m&7); value = hs*HSS
// h buffers: bf16 row-major [b][n][f].
// r20: k_prep FUSED into k_adj via last-block atomic pattern (device-scope
// atomics + agent fences, G16). Counters zeroed by hipMemsetAsync per launch.

// ---- Kernel 1: row L2-normalize x (f32) -> xnF (16 rows/block), iter 0 only ----
__global__ __launch_bounds__(256) void k_rownorm(const float* __restrict__ h,
                                                 unsigned short* __restrict__ xnF) {
    int t = threadIdx.x;
    int rl = t >> 4, j = t & 15;
    size_t row = (size_t)blockIdx.x * 16 + rl;
    const float* hr = h + row * FQ + j * 8;
    float v[8];
    #pragma unroll
    for (int e = 0; e < 8; ++e) v[e] = hr[e];
    float s = 0.f;
    #pragma unroll
    for (int e = 0; e < 8; ++e) s += v[e] * v[e];
    s += __shfl_xor(s, 1, 64);
    s += __shfl_xor(s, 2, 64);
    s += __shfl_xor(s, 4, 64);
    s += __shfl_xor(s, 8, 64);
    float inv = 1.0f / fmaxf(sqrtf(s), 1e-8f);
    us8 u;
    #pragma unroll
    for (int e = 0; e < 8; ++e) u[e] = f2bf(v[e] * inv);
    *(us8*)(xnF + (size_t)blockIdx.x * 2048 + j * 128 + rl * 8) = u;
}

// ---- Kernel 2 (r20): triangle S-tiles + fused prep (isq + hsF) for completed
//      128-row chunks. HSRC: 0 = f32 x, 1 = bf16 h. ----
template<int HSRC>
__global__ __launch_bounds__(512) void k_adjP(const unsigned short* __restrict__ xnF,
                                              unsigned char* __restrict__ adjF,
                                              float* __restrict__ dpart,
                                              unsigned int* __restrict__ cnt,
                                              const void* __restrict__ hsrc,
                                              float* __restrict__ isq,
                                              unsigned char* __restrict__ hsF,
                                              float t) {
    __shared__ unsigned short As[16384];                 // 32 KB: I panel
    __shared__ union { unsigned short Bsh[16384];        // 32 KB: J panel ...
                       unsigned char  T2[128 * 132]; } ub;  // ... reused as bounce
    __shared__ float dsm[2][128];
    __shared__ float csm[2][128];
    __shared__ float ivb[128];
    __shared__ int winI, winJ;

    int bid = blockIdx.x;
    int bb = bid & 7;                       // batch -> XCD locality
    int pr = bid >> 3;                      // pair index 0..135
    int I = 0;
    { int p = pr; while (p >= 16 - I) { p -= 16 - I; ++I; } pr = p; }
    int J = I + pr;

    int tid = threadIdx.x;
    int wid = tid >> 6, lane = tid & 63;
    int wr = wid >> 1, wc = wid & 1;        // 4 row-quarters x 2 col-halves
    int g = lane >> 4, c = lane & 15;

    const unsigned short* xb = xnF + (size_t)bb * NQ * FQ;
    int rowb = I * 128 + wr * 32;
    int colb = J * 128 + wc * 64;

    {   // stage panels (32 KB each, contiguous in xnF fragment layout)
        const unsigned short* srcA = xb + (size_t)(I * 8) * 2048;
        const unsigned short* srcB = xb + (size_t)(J * 8) * 2048;
        #pragma unroll
        for (int it = 0; it < 4; ++it) {
            __builtin_amdgcn_global_load_lds(
                (const __attribute__((address_space(1))) void*)(srcA + (size_t)(it * 512 + tid) * 8),
                (__attribute__((address_space(3))) void*)(As + (it * 512 + wid * 64) * 8),
                16, 0, 0);
            __builtin_amdgcn_global_load_lds(
                (const __attribute__((address_space(1))) void*)(srcB + (size_t)(it * 512 + tid) * 8),
                (__attribute__((address_space(3))) void*)(ub.Bsh + (it * 512 + wid * 64) * 8),
                16, 0, 0);
        }
    }
    __syncthreads();

    short8 a[2][4];
    #pragma unroll
    for (int mi = 0; mi < 2; ++mi)
        #pragma unroll
        for (int ks = 0; ks < 4; ++ks)
            a[mi][ks] = *(const short8*)(As + (wr * 2 + mi) * 2048 + (ks * 4 + g) * 128 + c * 8);

    f32x4 acc[2][4];
    #pragma unroll
    for (int mi = 0; mi < 2; ++mi)
        #pragma unroll
        for (int ni = 0; ni < 4; ++ni) acc[mi][ni] = (f32x4){0.f, 0.f, 0.f, 0.f};

    #pragma unroll
    for (int ni = 0; ni < 4; ++ni) {
        short8 b[4];
        #pragma unroll
        for (int ks = 0; ks < 4; ++ks)
            b[ks] = *(const short8*)(ub.Bsh + (wc * 4 + ni) * 2048 + (ks * 4 + g) * 128 + c * 8);
        #pragma unroll
        for (int mi = 0; mi < 2; ++mi)
            #pragma unroll
            for (int ks = 0; ks < 4; ++ks)
                acc[mi][ni] = __builtin_amdgcn_mfma_f32_16x16x32_bf16(a[mi][ks], b[ks], acc[mi][ni], 0, 0, 0);
    }

    __syncthreads();    // all Bsh reads done before T2 overlay writes

    unsigned char* adjb = adjF + (size_t)bb * NQ * NQ;
    float dl[2][4];
    float csl[4] = {0.f, 0.f, 0.f, 0.f};
    #pragma unroll
    for (int mi = 0; mi < 2; ++mi)
        #pragma unroll
        for (int r = 0; r < 4; ++r) dl[mi][r] = 0.f;

    #pragma unroll
    for (int mi = 0; mi < 2; ++mi)
        #pragma unroll
        for (int ni = 0; ni < 4; ++ni) {
            f32x4 v = acc[mi][ni];
            float x0 = (v[0] > t) ? v[0] : 0.0f;   // strict threshold in f32
            float x1 = (v[1] > t) ? v[1] : 0.0f;
            float x2 = (v[2] > t) ? v[2] : 0.0f;
            float x3 = (v[3] > t) ? v[3] : 0.0f;
            dl[mi][0] += x0; dl[mi][1] += x1; dl[mi][2] += x2; dl[mi][3] += x3;
            csl[ni] += x0 + x1 + x2 + x3;          // col partial (rows of this lane)
            unsigned int u = pk8lo(x0, x1, 0u);
            u = pk8hi(x2, x3, u);
            // store 1: mirror-transposed (n = col in J-range, m = row in I-range)
            *(unsigned int*)(adjb + (size_t)((colb >> 4) + ni) * NG
                                  + (size_t)((rowb >> 3) + mi * 2 + (g >> 1)) * 128
                                  + c * 8 + (g & 1) * 4) = u;
            // bounce for store 2 (skip on diagonal): T2[colL][rowL], stride 132
            if (I != J) {
                int colL = wc * 64 + ni * 16 + c;
                int rowL = wr * 32 + mi * 16 + g * 4;
                *(unsigned int*)(ub.T2 + colL * 132 + rowL) = u;
            }
        }

    // row sums -> dsm (reduce over c-lanes)
    #pragma unroll
    for (int mi = 0; mi < 2; ++mi)
        #pragma unroll
        for (int r = 0; r < 4; ++r) {
            float s = dl[mi][r];
            s += __shfl_xor(s, 1, 64);
            s += __shfl_xor(s, 2, 64);
            s += __shfl_xor(s, 4, 64);
            s += __shfl_xor(s, 8, 64);
            dl[mi][r] = s;
        }
    if (c == 0) {
        #pragma unroll
        for (int mi = 0; mi < 2; ++mi)
            #pragma unroll
            for (int r = 0; r < 4; ++r)
                dsm[wc][wr * 32 + mi * 16 + g * 4 + r] = dl[mi][r];
    }
    // col sums -> csm (reduce over g-lanes)
    if (I != J) {
        #pragma unroll
        for (int ni = 0; ni < 4; ++ni) {
            float s = csl[ni];
            s += __shfl_xor(s, 16, 64);
            s += __shfl_xor(s, 32, 64);
            csl[ni] = s;
        }
        if (lane < 16) {
            #pragma unroll
            for (int ni = 0; ni < 4; ++ni)
                csm[wr & 1][wc * 64 + ni * 16 + lane] = csl[ni];
        }
    }
    __syncthreads();
    if (I != J && (wr >= 2) && lane < 16) {
        #pragma unroll
        for (int ni = 0; ni < 4; ++ni)
            csm[wr & 1][wc * 64 + ni * 16 + lane] += csl[ni];
    }
    __syncthreads();

    // dpart writes
    if (tid < 128)
        dpart[((size_t)J * 8 + bb) * NQ + I * 128 + tid] = dsm[0][tid] + dsm[1][tid];
    if (I != J) {
        if (tid < 128)
            dpart[((size_t)I * 8 + bb) * NQ + J * 128 + tid] = csm[0][tid] + csm[1][tid];
        // store 2: direct orientation (n = row in I-range, m = col in J-range)
        int ng = wid;                 // 0..7 n-group within I-range
        int mg = lane >> 2;           // 0..15 m-group within J-range
        int part = lane & 3;          // n%16 quarter
        unsigned int w[8];
        #pragma unroll
        for (int ml = 0; ml < 8; ++ml)
            w[ml] = *(const unsigned int*)(ub.T2 + (mg * 8 + ml) * 132 + ng * 16 + part * 4);
        unsigned int o32[8];
        #pragma unroll
        for (int i = 0; i < 4; ++i)
            #pragma unroll
            for (int h = 0; h < 2; ++h)
                o32[i * 2 + h] = ((w[h * 4 + 0] >> (8 * i)) & 0xFFu)
                               | (((w[h * 4 + 1] >> (8 * i)) & 0xFFu) << 8)
                               | (((w[h * 4 + 2] >> (8 * i)) & 0xFFu) << 16)
                               | (((w[h * 4 + 3] >> (8 * i)) & 0xFFu) << 24);
        unsigned char* dst = adjb + (size_t)(I * 8 + ng) * NG + (size_t)(J * 16 + mg) * 128 + part * 32;
        *(u32x4*)dst        = (u32x4){o32[0], o32[1], o32[2], o32[3]};
        *(u32x4*)(dst + 16) = (u32x4){o32[4], o32[5], o32[6], o32[7]};
    }

    // ---- fused prep: last contributor per (bb, chunk) does isq + hsF ----
    __threadfence();                        // release: dpart stores device-visible
    __syncthreads();
    if (tid == 0)
        winI = (atomicAdd(&cnt[bb * 16 + I], 1u) == 15u) ? 1 : 0;
    if (tid == 1) {
        if (I != J) winJ = (atomicAdd(&cnt[bb * 16 + J], 1u) == 15u) ? 1 : 0;
        else        winJ = 0;
    }
    __syncthreads();
    __threadfence();                        // acquire: see other blocks' dpart

    #pragma unroll
    for (int wsel = 0; wsel < 2; ++wsel) {
        int win = wsel ? winJ : winI;       // block-uniform (LDS)
        int R   = wsel ? J : I;
        if (win) {
            if (tid < 128) {
                float s = 0.f;
                #pragma unroll
                for (int j = 0; j < 16; ++j)
                    s += dpart[((size_t)j * 8 + bb) * NQ + R * 128 + tid];
                float v = 1.0f / sqrtf(s);
                ivb[tid] = v;
                isq[(size_t)bb * NQ + R * 128 + tid] = v;
            }
            __syncthreads();
            unsigned char* hb = hsF + (size_t)bb * NQ * FQ;
            #pragma unroll
            for (int it2 = 0; it2 < 4; ++it2) {
                int p = tid + it2 * 512;
                int f = p & 127, mgl = p >> 7;       // mgl 0..15
                int mbase = R * 128 + mgl * 8;
                float sv[8];
                #pragma unroll
                for (int e = 0; e < 8; ++e) {
                    float hv = (HSRC == 0)
                        ? ((const float*)hsrc)[((size_t)bb * NQ + mbase + e) * FQ + f]
                        : bf2f(((const unsigned short*)hsrc)[((size_t)bb * NQ + mbase + e) * FQ + f]);
                    sv[e] = hv * ivb[mgl * 8 + e] * HSS;
                }
                u32x2 u;
                u[0] = pk8hi(sv[2], sv[3], pk8lo(sv[0], sv[1], 0u));
                u[1] = pk8hi(sv[6], sv[7], pk8lo(sv[4], sv[5], 0u));
                *(u32x2*)(hb + (size_t)(mbase >> 3) * 1024 + f * 8) = u;
            }
            __syncthreads();                // ivb safe to reuse for second chunk
        }
    }
}

// ---- Kernel 4 (r19): h_out = isq*(adjF_fp8 @ hsF_fp8)/HSS + in-block row-norm.
//      32-row blocks, grid 512 = 2 blocks/CU; 8 waves = 2 rg (16 rows) x 4 kh (K=512). ----
template<bool LAST>
__global__ __launch_bounds__(512) void k_gemm3(const unsigned char* __restrict__ adjF,
                                               const unsigned char* __restrict__ hsF,
                                               const float* __restrict__ isq,
                                               unsigned short* __restrict__ hout,
                                               unsigned short* __restrict__ xnF) {
    __shared__ unsigned char Bs[32768];        // 4 kh regions x 8 KB phase slice
    __shared__ float red[32][128];             // 16 KB f32 partial-sum buffer

    int bid = blockIdx.x;
    int lb = (bid & 7) * 64 + (bid >> 3);      // XCD swizzle (grid 512)
    int bb = lb >> 6;
    int rt = lb & 63;
    int row0g = rt * 32;
    int tid = threadIdx.x;
    int wid = tid >> 6, lane = tid & 63;
    int g = lane >> 4, c = lane & 15;
    int rg = wid >> 2, kh = wid & 3;
    int wrow = row0g + rg * 16;                // this wave's single n-group

    const unsigned char* adjr = adjF + (size_t)bb * NQ * NQ + (size_t)(wrow >> 4) * NG;
    const unsigned char* hb   = hsF + (size_t)bb * NQ * FQ;

    f32x4 acc[8];
    #pragma unroll
    for (int i = 0; i < 8; ++i) acc[i] = (f32x4){0.f, 0.f, 0.f, 0.f};

    int khr = wid >> 1;            // staging region this wave fills (2 waves/region)
    int wlo = wid & 1;

    for (int ph = 0; ph < 8; ++ph) {
        __syncthreads();           // previous phase's readers done
        {
            const unsigned char* src = hb + (size_t)(khr * 64 + ph * 8) * 1024 + wlo * 1024;
            unsigned char* dst = Bs + khr * 8192 + wlo * 1024;
            #pragma unroll
            for (int it = 0; it < 4; ++it) {
                __builtin_amdgcn_global_load_lds(
                    (const __attribute__((address_space(1))) void*)(src + it * 2048 + lane * 16),
                    (__attribute__((address_space(3))) void*)(dst + it * 2048),
                    16, 0, 0);
            }
        }
        __syncthreads();           // drains vmcnt
        #pragma unroll
        for (int kk2 = 0; kk2 < 2; ++kk2) {
            int mstep = kh * 16 + ph * 2 + kk2;     // global 32-elem K step
            long a0 = *(const long*)(adjr + (size_t)(mstep * 4 + g) * 128 + c * 8);
            #pragma unroll
            for (int ct = 0; ct < 8; ++ct) {
                long bfr = *(const long*)(Bs + kh * 8192 + kk2 * 4096 + g * 1024 + (ct * 16 + c) * 8);
                acc[ct] = __builtin_amdgcn_mfma_f32_16x16x32_fp8_fp8(a0, bfr, acc[ct], 0, 0, 0);
            }
        }
    }

    // cross-kh reduction into red (barrier-ordered, deterministic)
    __syncthreads();
    #pragma unroll
    for (int s = 0; s < 4; ++s) {
        if (kh == s) {
            #pragma unroll
            for (int ct = 0; ct < 8; ++ct)
                #pragma unroll
                for (int r = 0; r < 4; ++r) {
                    int rl = rg * 16 + g * 4 + r;
                    if (s == 0) red[rl][ct * 16 + c] = acc[ct][r];
                    else        red[rl][ct * 16 + c] += acc[ct][r];
                }
        }
        __syncthreads();
    }

    // final pass: scale, row-norm, write h bf16 (+ xnF fragments unless LAST)
    int rl = tid >> 4;             // 0..31
    int j  = tid & 15;             // 16 f-chunks of 8
    int n  = row0g + rl;
    float scale = isq[(size_t)bb * NQ + n] * (1.0f / HSS);
    float v[8];
    float s = 0.f;
    #pragma unroll
    for (int e = 0; e < 8; ++e) {
        float x = red[rl][j * 8 + e] * scale;
        v[e] = x;
        s += x * x;
    }
    s += __shfl_xor(s, 1, 64);
    s += __shfl_xor(s, 2, 64);
    s += __shfl_xor(s, 4, 64);
    s += __shfl_xor(s, 8, 64);
    float inv = 1.0f / fmaxf(sqrtf(s), 1e-8f);

    us8 h0;
    #pragma unroll
    for (int e = 0; e < 8; ++e) h0[e] = f2bf(v[e]);
    *(us8*)(hout + ((size_t)bb * NQ + n) * FQ + j * 8) = h0;

    if constexpr (!LAST) {
        us8 u0;
        #pragma unroll
        for (int e = 0; e < 8; ++e) u0[e] = f2bf(v[e] * inv);
        unsigned short* xd = xnF + (size_t)bb * NQ * FQ + (size_t)(n >> 4) * 2048
                                 + j * 128 + (n & 15) * 8;
        *(us8*)xd = u0;
    }
}

// ---- Kernel 5: out = (h3(bf16) + x) @ W ----
__global__ __launch_bounds__(256) void k_out(const unsigned short* __restrict__ h3,
                                             const float* __restrict__ x,
                                             const float* __restrict__ W,
                                             float* __restrict__ out) {
    __shared__ float hx[8][128];
    int r0 = blockIdx.x * 8;
    int tid = threadIdx.x;
    #pragma unroll
    for (int it = 0; it < 4; ++it) {
        int idx = tid + it * 256;
        int ri = idx >> 7, f = idx & 127;
        size_t gi = (size_t)(r0 + ri) * FQ + f;
        hx[ri][f] = bf2f(h3[gi]) + x[gi];
    }
    __syncthreads();
    int o = tid & 127, half = tid >> 7;
    float acc[4] = {0.f, 0.f, 0.f, 0.f};
    for (int f = 0; f < 128; ++f) {
        float wv = W[f * 128 + o];
        #pragma unroll
        for (int j = 0; j < 4; ++j)
            acc[j] += hx[half * 4 + j][f] * wv;
    }
    #pragma unroll
    for (int j = 0; j < 4; ++j)
        out[(size_t)(r0 + half * 4 + j) * FQ + o] = acc[j];
}

extern "C" void kernel_launch(void* const* d_in, const int* in_sizes, int n_in,
                              void* d_out, int out_size, void* d_ws, size_t ws_size,
                              hipStream_t stream) {
    const float* x = (const float*)d_in[0];
    const float* W = (const float*)d_in[1];
    float* out = (float*)d_out;
    char* ws = (char*)d_ws;

    const size_t CS   = (size_t)BQ * NQ * FQ;
    const size_t oADJ = 0;
    const size_t oXN  = oADJ + (size_t)BQ * NQ * NQ;          // 32 MiB fp8 adj
    const size_t oHST = oXN  + CS * 2;                        // +4 MiB bf16 xn
    const size_t oD   = oHST + CS;                            // +2 MiB fp8 hs
    const size_t oISQ = oD   + (size_t)16 * BQ * NQ * 4;      // +1 MiB
    const size_t oCNT = oISQ + (size_t)BQ * NQ * 4;           // +64 KiB
    const size_t oHA  = oCNT + 3 * 128 * 4;                   // +1.5 KiB counters
    const size_t oHB  = oHA  + CS * 2;                        // +4 MiB bf16 hA
    const size_t need = oHB  + CS * 2;                        // +4 MiB bf16 hB
    if (ws_size < need) return;   // diagnostic: output stays poisoned

    unsigned char*  adjF = (unsigned char*)(ws + oADJ);
    unsigned short* xnF  = (unsigned short*)(ws + oXN);
    unsigned char*  hsF  = (unsigned char*)(ws + oHST);
    float* dpart = (float*)(ws + oD);
    float* isq   = (float*)(ws + oISQ);
    unsigned int* cnt = (unsigned int*)(ws + oCNT);
    unsigned short* hA = (unsigned short*)(ws + oHA);
    unsigned short* hB = (unsigned short*)(ws + oHB);

    const float ts[3] = {0.05f, 0.1f, 0.15f};

    hipMemsetAsync(cnt, 0, 3 * 128 * 4, stream);   // deterministic across replays

    // iter 0
    k_rownorm<<<BQ * NQ / 16, 256, 0, stream>>>(x, xnF);
    k_adjP<0><<<BQ * 136, 512, 0, stream>>>(xnF, adjF, dpart, cnt + 0 * 128, x, isq, hsF, ts[0]);
    k_gemm3<false><<<BQ * 64, 512, 0, stream>>>(adjF, hsF, isq, hA, xnF);
    // iter 1
    k_adjP<1><<<BQ * 136, 512, 0, stream>>>(xnF, adjF, dpart, cnt + 1 * 128, hA, isq, hsF, ts[1]);
    k_gemm3<false><<<BQ * 64, 512, 0, stream>>>(adjF, hsF, isq, hB, xnF);
    // iter 2
    k_adjP<1><<<BQ * 136, 512, 0, stream>>>(xnF, adjF, dpart, cnt + 2 * 128, hB, isq, hsF, ts[2]);
    k_gemm3<true><<<BQ * 64, 512, 0, stream>>>(adjF, hsF, isq, hA, xnF);

    k_out<<<BQ * NQ / 8, 256, 0, stream>>>(hA, x, W, out);
}

// Round 21
// 136.361 us; speedup vs baseline: 9.4961x; 9.4961x over previous
//
#include <hip/hip_runtime.h>
#include <hip/hip_bf16.h>
#include <cstdint>

#define BQ 8
#define NQ 2048
#define FQ 128
#define NG (NQ * 16)            // adjF n-group stride in BYTES (fp8)
#define HSS 256.0f              // hs fp8 scale

typedef __attribute__((ext_vector_type(8))) short short8;
typedef __attribute__((ext_vector_type(4))) float f32x4;
typedef __attribute__((ext_vector_type(8))) unsigned short us8;
typedef __attribute__((ext_vector_type(2))) unsigned int u32x2;
typedef __attribute__((ext_vector_type(4))) unsigned int u32x4;

__device__ __forceinline__ unsigned short f2bf(float f) {
    union { float f; unsigned int u; } c; c.f = f;
    unsigned int u = c.u;
    u = (u + 0x7FFFu + ((u >> 16) & 1u)) >> 16;   // RNE
    return (unsigned short)u;
}
__device__ __forceinline__ float bf2f(unsigned short u) {
    union { unsigned int i; float f; } c; c.i = (unsigned int)u << 16; return c.f;
}
__device__ __forceinline__ unsigned int pk8lo(float a, float b, unsigned int old) {
    return (unsigned int)__builtin_amdgcn_cvt_pk_fp8_f32(a, b, (int)old, false);
}
__device__ __forceinline__ unsigned int pk8hi(float a, float b, unsigned int old) {
    return (unsigned int)__builtin_amdgcn_cvt_pk_fp8_f32(a, b, (int)old, true);
}

// Layouts (per batch):
//   xnF : bf16 [n/16][k/8][n%16][k%8]  elem addr = (n>>4)*2048 + (k>>3)*128 + (n&15)*8 + (k&7)
//   adjF: fp8  [n/16][m/8][n%16][m%8]  BYTE addr = (n>>4)*NG + (m>>3)*128 + (n&15)*8 + (m&7)
//   hsF : fp8  [m/8][f][m%8]           BYTE addr = (m>>3)*1024 + f*8 + (m&7); value = hs*HSS
// h buffers: bf16 row-major [b][n][f].
// r21: exact r19 revert (r20's per-block device fences caused a 10x stall —
// cross-block fusion via device-scope fences is only viable when fences are
// per-grid-rare, never per-block).

// ---- Kernel 1: row L2-normalize x (f32) -> xnF (16 rows/block), iter 0 only ----
__global__ __launch_bounds__(256) void k_rownorm(const float* __restrict__ h,
                                                 unsigned short* __restrict__ xnF) {
    int t = threadIdx.x;
    int rl = t >> 4, j = t & 15;
    size_t row = (size_t)blockIdx.x * 16 + rl;
    const float* hr = h + row * FQ + j * 8;
    float v[8];
    #pragma unroll
    for (int e = 0; e < 8; ++e) v[e] = hr[e];
    float s = 0.f;
    #pragma unroll
    for (int e = 0; e < 8; ++e) s += v[e] * v[e];
    s += __shfl_xor(s, 1, 64);
    s += __shfl_xor(s, 2, 64);
    s += __shfl_xor(s, 4, 64);
    s += __shfl_xor(s, 8, 64);
    float inv = 1.0f / fmaxf(sqrtf(s), 1e-8f);
    us8 u;
    #pragma unroll
    for (int e = 0; e < 8; ++e) u[e] = f2bf(v[e] * inv);
    *(us8*)(xnF + (size_t)blockIdx.x * 2048 + j * 128 + rl * 8) = u;
}

// ---- Kernel 2 (r18): triangle S-tiles. Grid = 8 batches x 136 (I<=J) pairs. ----
__global__ __launch_bounds__(512) void k_adj(const unsigned short* __restrict__ xnF,
                                             unsigned char* __restrict__ adjF,
                                             float* __restrict__ dpart, float t) {
    __shared__ unsigned short As[16384];                 // 32 KB: I panel
    __shared__ union { unsigned short Bsh[16384];        // 32 KB: J panel ...
                       unsigned char  T2[128 * 132]; } ub;  // ... reused as bounce
    __shared__ float dsm[2][128];
    __shared__ float csm[2][128];

    int bid = blockIdx.x;
    int bb = bid & 7;                       // batch -> XCD locality
    int pr = bid >> 3;                      // pair index 0..135
    int I = 0;
    { int p = pr; while (p >= 16 - I) { p -= 16 - I; ++I; } pr = p; }
    int J = I + pr;

    int tid = threadIdx.x;
    int wid = tid >> 6, lane = tid & 63;
    int wr = wid >> 1, wc = wid & 1;        // 4 row-quarters x 2 col-halves
    int g = lane >> 4, c = lane & 15;

    const unsigned short* xb = xnF + (size_t)bb * NQ * FQ;
    int rowb = I * 128 + wr * 32;
    int colb = J * 128 + wc * 64;

    {   // stage panels (32 KB each, contiguous in xnF fragment layout)
        const unsigned short* srcA = xb + (size_t)(I * 8) * 2048;
        const unsigned short* srcB = xb + (size_t)(J * 8) * 2048;
        #pragma unroll
        for (int it = 0; it < 4; ++it) {
            __builtin_amdgcn_global_load_lds(
                (const __attribute__((address_space(1))) void*)(srcA + (size_t)(it * 512 + tid) * 8),
                (__attribute__((address_space(3))) void*)(As + (it * 512 + wid * 64) * 8),
                16, 0, 0);
            __builtin_amdgcn_global_load_lds(
                (const __attribute__((address_space(1))) void*)(srcB + (size_t)(it * 512 + tid) * 8),
                (__attribute__((address_space(3))) void*)(ub.Bsh + (it * 512 + wid * 64) * 8),
                16, 0, 0);
        }
    }
    __syncthreads();

    short8 a[2][4];
    #pragma unroll
    for (int mi = 0; mi < 2; ++mi)
        #pragma unroll
        for (int ks = 0; ks < 4; ++ks)
            a[mi][ks] = *(const short8*)(As + (wr * 2 + mi) * 2048 + (ks * 4 + g) * 128 + c * 8);

    f32x4 acc[2][4];
    #pragma unroll
    for (int mi = 0; mi < 2; ++mi)
        #pragma unroll
        for (int ni = 0; ni < 4; ++ni) acc[mi][ni] = (f32x4){0.f, 0.f, 0.f, 0.f};

    #pragma unroll
    for (int ni = 0; ni < 4; ++ni) {
        short8 b[4];
        #pragma unroll
        for (int ks = 0; ks < 4; ++ks)
            b[ks] = *(const short8*)(ub.Bsh + (wc * 4 + ni) * 2048 + (ks * 4 + g) * 128 + c * 8);
        #pragma unroll
        for (int mi = 0; mi < 2; ++mi)
            #pragma unroll
            for (int ks = 0; ks < 4; ++ks)
                acc[mi][ni] = __builtin_amdgcn_mfma_f32_16x16x32_bf16(a[mi][ks], b[ks], acc[mi][ni], 0, 0, 0);
    }

    __syncthreads();    // all Bsh reads done before T2 overlay writes

    unsigned char* adjb = adjF + (size_t)bb * NQ * NQ;
    float dl[2][4];
    float csl[4] = {0.f, 0.f, 0.f, 0.f};
    #pragma unroll
    for (int mi = 0; mi < 2; ++mi)
        #pragma unroll
        for (int r = 0; r < 4; ++r) dl[mi][r] = 0.f;

    #pragma unroll
    for (int mi = 0; mi < 2; ++mi)
        #pragma unroll
        for (int ni = 0; ni < 4; ++ni) {
            f32x4 v = acc[mi][ni];
            float x0 = (v[0] > t) ? v[0] : 0.0f;   // strict threshold in f32
            float x1 = (v[1] > t) ? v[1] : 0.0f;
            float x2 = (v[2] > t) ? v[2] : 0.0f;
            float x3 = (v[3] > t) ? v[3] : 0.0f;
            dl[mi][0] += x0; dl[mi][1] += x1; dl[mi][2] += x2; dl[mi][3] += x3;
            csl[ni] += x0 + x1 + x2 + x3;          // col partial (rows of this lane)
            unsigned int u = pk8lo(x0, x1, 0u);
            u = pk8hi(x2, x3, u);
            // store 1: mirror-transposed (n = col in J-range, m = row in I-range)
            *(unsigned int*)(adjb + (size_t)((colb >> 4) + ni) * NG
                                  + (size_t)((rowb >> 3) + mi * 2 + (g >> 1)) * 128
                                  + c * 8 + (g & 1) * 4) = u;
            // bounce for store 2 (skip on diagonal): T2[colL][rowL], stride 132
            if (I != J) {
                int colL = wc * 64 + ni * 16 + c;
                int rowL = wr * 32 + mi * 16 + g * 4;
                *(unsigned int*)(ub.T2 + colL * 132 + rowL) = u;
            }
        }

    // row sums -> dsm (reduce over c-lanes)
    #pragma unroll
    for (int mi = 0; mi < 2; ++mi)
        #pragma unroll
        for (int r = 0; r < 4; ++r) {
            float s = dl[mi][r];
            s += __shfl_xor(s, 1, 64);
            s += __shfl_xor(s, 2, 64);
            s += __shfl_xor(s, 4, 64);
            s += __shfl_xor(s, 8, 64);
            dl[mi][r] = s;
        }
    if (c == 0) {
        #pragma unroll
        for (int mi = 0; mi < 2; ++mi)
            #pragma unroll
            for (int r = 0; r < 4; ++r)
                dsm[wc][wr * 32 + mi * 16 + g * 4 + r] = dl[mi][r];
    }
    // col sums -> csm (reduce over g-lanes)
    if (I != J) {
        #pragma unroll
        for (int ni = 0; ni < 4; ++ni) {
            float s = csl[ni];
            s += __shfl_xor(s, 16, 64);
            s += __shfl_xor(s, 32, 64);
            csl[ni] = s;
        }
        if (lane < 16) {
            #pragma unroll
            for (int ni = 0; ni < 4; ++ni)
                csm[wr & 1][wc * 64 + ni * 16 + lane] = csl[ni];
        }
    }
    __syncthreads();
    if (I != J && (wr >= 2) && lane < 16) {
        #pragma unroll
        for (int ni = 0; ni < 4; ++ni)
            csm[wr & 1][wc * 64 + ni * 16 + lane] += csl[ni];
    }
    __syncthreads();

    // dpart writes
    if (tid < 128)
        dpart[((size_t)J * 8 + bb) * NQ + I * 128 + tid] = dsm[0][tid] + dsm[1][tid];
    if (I != J) {
        if (tid < 128)
            dpart[((size_t)I * 8 + bb) * NQ + J * 128 + tid] = csm[0][tid] + csm[1][tid];
        // store 2: direct orientation (n = row in I-range, m = col in J-range)
        int ng = wid;                 // 0..7 n-group within I-range
        int mg = lane >> 2;           // 0..15 m-group within J-range
        int part = lane & 3;          // n%16 quarter
        unsigned int w[8];
        #pragma unroll
        for (int ml = 0; ml < 8; ++ml)
            w[ml] = *(const unsigned int*)(ub.T2 + (mg * 8 + ml) * 132 + ng * 16 + part * 4);
        unsigned int o32[8];
        #pragma unroll
        for (int i = 0; i < 4; ++i)
            #pragma unroll
            for (int h = 0; h < 2; ++h)
                o32[i * 2 + h] = ((w[h * 4 + 0] >> (8 * i)) & 0xFFu)
                               | (((w[h * 4 + 1] >> (8 * i)) & 0xFFu) << 8)
                               | (((w[h * 4 + 2] >> (8 * i)) & 0xFFu) << 16)
                               | (((w[h * 4 + 3] >> (8 * i)) & 0xFFu) << 24);
        unsigned char* dst = adjb + (size_t)(I * 8 + ng) * NG + (size_t)(J * 16 + mg) * 128 + part * 32;
        *(u32x4*)dst        = (u32x4){o32[0], o32[1], o32[2], o32[3]};
        *(u32x4*)(dst + 16) = (u32x4){o32[4], o32[5], o32[6], o32[7]};
    }
}

// ---- Kernel 3a (iter 0): isq from dpart; hsF (fp8, xHSS) from f32 x ----
__global__ __launch_bounds__(256) void k_prep_f32(const float* __restrict__ h,
                                                  const float* __restrict__ dpart,
                                                  float* __restrict__ isq,
                                                  unsigned char* __restrict__ hsF) {
    __shared__ float tile[32][129];
    __shared__ float iv[32];
    int r0 = blockIdx.x * 32;
    int bb = r0 >> 11;
    int m0 = r0 & (NQ - 1);
    int tid = threadIdx.x;
    if (tid < 32) {
        float s = 0.f;
        #pragma unroll
        for (int j = 0; j < 16; ++j)
            s += dpart[((size_t)j * 8 + bb) * NQ + m0 + tid];
        float v = 1.0f / sqrtf(s);
        iv[tid] = v;
        isq[r0 + tid] = v;
    }
    #pragma unroll
    for (int it = 0; it < 16; ++it) {
        int idx = tid + it * 256;
        int mi = idx >> 7, f = idx & 127;
        tile[mi][f] = h[(size_t)(r0 + mi) * FQ + f];
    }
    __syncthreads();
    unsigned char* hb = hsF + (size_t)bb * NQ * FQ;
    #pragma unroll
    for (int it = 0; it < 2; ++it) {
        int p = tid + it * 256;
        int f = p & 127, mc = p >> 7;
        float sv[8];
        #pragma unroll
        for (int e = 0; e < 8; ++e)
            sv[e] = tile[mc * 8 + e][f] * iv[mc * 8 + e] * HSS;
        u32x2 u;
        u[0] = pk8hi(sv[2], sv[3], pk8lo(sv[0], sv[1], 0u));
        u[1] = pk8hi(sv[6], sv[7], pk8lo(sv[4], sv[5], 0u));
        *(u32x2*)(hb + (size_t)((m0 >> 3) + mc) * 1024 + f * 8) = u;
    }
}

// ---- Kernel 3b (iters 1,2): isq from dpart; hsF (fp8) from bf16 h ----
__global__ __launch_bounds__(256) void k_prep_bf16(const unsigned short* __restrict__ h,
                                                   const float* __restrict__ dpart,
                                                   float* __restrict__ isq,
                                                   unsigned char* __restrict__ hsF) {
    __shared__ float tile[32][129];
    __shared__ float iv[32];
    int r0 = blockIdx.x * 32;
    int bb = r0 >> 11;
    int m0 = r0 & (NQ - 1);
    int tid = threadIdx.x;
    if (tid < 32) {
        float s = 0.f;
        #pragma unroll
        for (int j = 0; j < 16; ++j)
            s += dpart[((size_t)j * 8 + bb) * NQ + m0 + tid];
        float v = 1.0f / sqrtf(s);
        iv[tid] = v;
        isq[r0 + tid] = v;
    }
    #pragma unroll
    for (int it = 0; it < 16; ++it) {
        int idx = tid + it * 256;
        int mi = idx >> 7, f = idx & 127;
        tile[mi][f] = bf2f(h[(size_t)(r0 + mi) * FQ + f]);
    }
    __syncthreads();
    unsigned char* hb = hsF + (size_t)bb * NQ * FQ;
    #pragma unroll
    for (int it = 0; it < 2; ++it) {
        int p = tid + it * 256;
        int f = p & 127, mc = p >> 7;
        float sv[8];
        #pragma unroll
        for (int e = 0; e < 8; ++e)
            sv[e] = tile[mc * 8 + e][f] * iv[mc * 8 + e] * HSS;
        u32x2 u;
        u[0] = pk8hi(sv[2], sv[3], pk8lo(sv[0], sv[1], 0u));
        u[1] = pk8hi(sv[6], sv[7], pk8lo(sv[4], sv[5], 0u));
        *(u32x2*)(hb + (size_t)((m0 >> 3) + mc) * 1024 + f * 8) = u;
    }
}

// ---- Kernel 4 (r19): h_out = isq*(adjF_fp8 @ hsF_fp8)/HSS + in-block row-norm.
//      32-row blocks, grid 512 = 2 blocks/CU; 8 waves = 2 rg (16 rows) x 4 kh (K=512). ----
template<bool LAST>
__global__ __launch_bounds__(512) void k_gemm3(const unsigned char* __restrict__ adjF,
                                               const unsigned char* __restrict__ hsF,
                                               const float* __restrict__ isq,
                                               unsigned short* __restrict__ hout,
                                               unsigned short* __restrict__ xnF) {
    __shared__ unsigned char Bs[32768];        // 4 kh regions x 8 KB phase slice
    __shared__ float red[32][128];             // 16 KB f32 partial-sum buffer

    int bid = blockIdx.x;
    int lb = (bid & 7) * 64 + (bid >> 3);      // XCD swizzle (grid 512)
    int bb = lb >> 6;
    int rt = lb & 63;
    int row0g = rt * 32;
    int tid = threadIdx.x;
    int wid = tid >> 6, lane = tid & 63;
    int g = lane >> 4, c = lane & 15;
    int rg = wid >> 2, kh = wid & 3;
    int wrow = row0g + rg * 16;                // this wave's single n-group

    const unsigned char* adjr = adjF + (size_t)bb * NQ * NQ + (size_t)(wrow >> 4) * NG;
    const unsigned char* hb   = hsF + (size_t)bb * NQ * FQ;

    f32x4 acc[8];
    #pragma unroll
    for (int i = 0; i < 8; ++i) acc[i] = (f32x4){0.f, 0.f, 0.f, 0.f};

    int khr = wid >> 1;            // staging region this wave fills (2 waves/region)
    int wlo = wid & 1;

    for (int ph = 0; ph < 8; ++ph) {
        __syncthreads();           // previous phase's readers done
        {
            const unsigned char* src = hb + (size_t)(khr * 64 + ph * 8) * 1024 + wlo * 1024;
            unsigned char* dst = Bs + khr * 8192 + wlo * 1024;
            #pragma unroll
            for (int it = 0; it < 4; ++it) {
                __builtin_amdgcn_global_load_lds(
                    (const __attribute__((address_space(1))) void*)(src + it * 2048 + lane * 16),
                    (__attribute__((address_space(3))) void*)(dst + it * 2048),
                    16, 0, 0);
            }
        }
        __syncthreads();           // drains vmcnt
        #pragma unroll
        for (int kk2 = 0; kk2 < 2; ++kk2) {
            int mstep = kh * 16 + ph * 2 + kk2;     // global 32-elem K step
            long a0 = *(const long*)(adjr + (size_t)(mstep * 4 + g) * 128 + c * 8);
            #pragma unroll
            for (int ct = 0; ct < 8; ++ct) {
                long bfr = *(const long*)(Bs + kh * 8192 + kk2 * 4096 + g * 1024 + (ct * 16 + c) * 8);
                acc[ct] = __builtin_amdgcn_mfma_f32_16x16x32_fp8_fp8(a0, bfr, acc[ct], 0, 0, 0);
            }
        }
    }

    // cross-kh reduction into red (barrier-ordered, deterministic)
    __syncthreads();
    #pragma unroll
    for (int s = 0; s < 4; ++s) {
        if (kh == s) {
            #pragma unroll
            for (int ct = 0; ct < 8; ++ct)
                #pragma unroll
                for (int r = 0; r < 4; ++r) {
                    int rl = rg * 16 + g * 4 + r;
                    if (s == 0) red[rl][ct * 16 + c] = acc[ct][r];
                    else        red[rl][ct * 16 + c] += acc[ct][r];
                }
        }
        __syncthreads();
    }

    // final pass: scale, row-norm, write h bf16 (+ xnF fragments unless LAST)
    int rl = tid >> 4;             // 0..31
    int j  = tid & 15;             // 16 f-chunks of 8
    int n  = row0g + rl;
    float scale = isq[(size_t)bb * NQ + n] * (1.0f / HSS);
    float v[8];
    float s = 0.f;
    #pragma unroll
    for (int e = 0; e < 8; ++e) {
        float x = red[rl][j * 8 + e] * scale;
        v[e] = x;
        s += x * x;
    }
    s += __shfl_xor(s, 1, 64);
    s += __shfl_xor(s, 2, 64);
    s += __shfl_xor(s, 4, 64);
    s += __shfl_xor(s, 8, 64);
    float inv = 1.0f / fmaxf(sqrtf(s), 1e-8f);

    us8 h0;
    #pragma unroll
    for (int e = 0; e < 8; ++e) h0[e] = f2bf(v[e]);
    *(us8*)(hout + ((size_t)bb * NQ + n) * FQ + j * 8) = h0;

    if constexpr (!LAST) {
        us8 u0;
        #pragma unroll
        for (int e = 0; e < 8; ++e) u0[e] = f2bf(v[e] * inv);
        unsigned short* xd = xnF + (size_t)bb * NQ * FQ + (size_t)(n >> 4) * 2048
                                 + j * 128 + (n & 15) * 8;
        *(us8*)xd = u0;
    }
}

// ---- Kernel 5: out = (h3(bf16) + x) @ W ----
__global__ __launch_bounds__(256) void k_out(const unsigned short* __restrict__ h3,
                                             const float* __restrict__ x,
                                             const float* __restrict__ W,
                                             float* __restrict__ out) {
    __shared__ float hx[8][128];
    int r0 = blockIdx.x * 8;
    int tid = threadIdx.x;
    #pragma unroll
    for (int it = 0; it < 4; ++it) {
        int idx = tid + it * 256;
        int ri = idx >> 7, f = idx & 127;
        size_t gi = (size_t)(r0 + ri) * FQ + f;
        hx[ri][f] = bf2f(h3[gi]) + x[gi];
    }
    __syncthreads();
    int o = tid & 127, half = tid >> 7;
    float acc[4] = {0.f, 0.f, 0.f, 0.f};
    for (int f = 0; f < 128; ++f) {
        float wv = W[f * 128 + o];
        #pragma unroll
        for (int j = 0; j < 4; ++j)
            acc[j] += hx[half * 4 + j][f] * wv;
    }
    #pragma unroll
    for (int j = 0; j < 4; ++j)
        out[(size_t)(r0 + half * 4 + j) * FQ + o] = acc[j];
}

extern "C" void kernel_launch(void* const* d_in, const int* in_sizes, int n_in,
                              void* d_out, int out_size, void* d_ws, size_t ws_size,
                              hipStream_t stream) {
    const float* x = (const float*)d_in[0];
    const float* W = (const float*)d_in[1];
    float* out = (float*)d_out;
    char* ws = (char*)d_ws;

    const size_t CS   = (size_t)BQ * NQ * FQ;
    const size_t oADJ = 0;
    const size_t oXN  = oADJ + (size_t)BQ * NQ * NQ;          // 32 MiB fp8 adj
    const size_t oHST = oXN  + CS * 2;                        // +4 MiB bf16 xn
    const size_t oD   = oHST + CS;                            // +2 MiB fp8 hs
    const size_t oISQ = oD   + (size_t)16 * BQ * NQ * 4;      // +1 MiB
    const size_t oHA  = oISQ + (size_t)BQ * NQ * 4;           // +64 KiB
    const size_t oHB  = oHA  + CS * 2;                        // +4 MiB bf16 hA
    const size_t need = oHB  + CS * 2;                        // +4 MiB bf16 hB
    if (ws_size < need) return;   // diagnostic: output stays poisoned

    unsigned char*  adjF = (unsigned char*)(ws + oADJ);
    unsigned short* xnF  = (unsigned short*)(ws + oXN);
    unsigned char*  hsF  = (unsigned char*)(ws + oHST);
    float* dpart = (float*)(ws + oD);
    float* isq   = (float*)(ws + oISQ);
    unsigned short* hA = (unsigned short*)(ws + oHA);
    unsigned short* hB = (unsigned short*)(ws + oHB);

    const float ts[3] = {0.05f, 0.1f, 0.15f};

    // iter 0
    k_rownorm<<<BQ * NQ / 16, 256, 0, stream>>>(x, xnF);
    k_adj<<<BQ * 136, 512, 0, stream>>>(xnF, adjF, dpart, ts[0]);
    k_prep_f32<<<BQ * NQ / 32, 256, 0, stream>>>(x, dpart, isq, hsF);
    k_gemm3<false><<<BQ * 64, 512, 0, stream>>>(adjF, hsF, isq, hA, xnF);
    // iter 1
    k_adj<<<BQ * 136, 512, 0, stream>>>(xnF, adjF, dpart, ts[1]);
    k_prep_bf16<<<BQ * NQ / 32, 256, 0, stream>>>(hA, dpart, isq, hsF);
    k_gemm3<false><<<BQ * 64, 512, 0, stream>>>(adjF, hsF, isq, hB, xnF);
    // iter 2
    k_adj<<<BQ * 136, 512, 0, stream>>>(xnF, adjF, dpart, ts[2]);
    k_prep_bf16<<<BQ * NQ / 32, 256, 0, stream>>>(hB, dpart, isq, hsF);
    k_gemm3<true><<<BQ * 64, 512, 0, stream>>>(adjF, hsF, isq, hA, xnF);

    k_out<<<BQ * NQ / 8, 256, 0, stream>>>(hA, x, W, out);
}

// Round 22
// 122.863 us; speedup vs baseline: 10.5393x; 1.1099x over previous
//
#include <hip/hip_runtime.h>
#include <hip/hip_bf16.h>
#include <cstdint>

#define BQ 8
#define NQ 2048
#define FQ 128
#define NG (NQ * 16)            // adjF n-group stride in BYTES (fp8)
#define HSS 256.0f              // hs fp8 scale

typedef __attribute__((ext_vector_type(8))) short short8;
typedef __attribute__((ext_vector_type(4))) float f32x4;
typedef __attribute__((ext_vector_type(8))) unsigned short us8;
typedef __attribute__((ext_vector_type(2))) unsigned int u32x2;
typedef __attribute__((ext_vector_type(4))) unsigned int u32x4;

__device__ __forceinline__ unsigned short f2bf(float f) {
    union { float f; unsigned int u; } c; c.f = f;
    unsigned int u = c.u;
    u = (u + 0x7FFFu + ((u >> 16) & 1u)) >> 16;   // RNE
    return (unsigned short)u;
}
__device__ __forceinline__ float bf2f(unsigned short u) {
    union { unsigned int i; float f; } c; c.i = (unsigned int)u << 16; return c.f;
}
__device__ __forceinline__ unsigned int pk8lo(float a, float b, unsigned int old) {
    return (unsigned int)__builtin_amdgcn_cvt_pk_fp8_f32(a, b, (int)old, false);
}
__device__ __forceinline__ unsigned int pk8hi(float a, float b, unsigned int old) {
    return (unsigned int)__builtin_amdgcn_cvt_pk_fp8_f32(a, b, (int)old, true);
}

// Layouts (per batch):
//   xnF : bf16 [n/16][k/8][n%16][k%8]  elem addr = (n>>4)*2048 + (k>>3)*128 + (n&15)*8 + (k&7)
//   adjF: fp8  [n/16][m/8][n%16][m%8]  BYTE addr = (n>>4)*NG + (m>>3)*128 + (n&15)*8 + (m&7)
//   hsF : fp8  [m/8][f][m%8]           BYTE addr = (m>>3)*1024 + f*8 + (m&7); value = hs*HSS
//   WF  : bf16 [o/16][f/8][o%16][f%8]  (W fragment layout, B-operand; built by k_wprep)
// h buffers: bf16 row-major [b][n][f].
// r22: k_out FUSED into LAST k_gemm3 epilogue (MFMA against WF; bf16(h3+x) in
// swizzled LDS). hA round-trip in last iter deleted; k_out kernel deleted.

// ---- Kernel 0 (once): WF[o/16][f/8][o%16][f%8] = bf16(W[f][o]) ----
__global__ __launch_bounds__(256) void k_wprep(const float* __restrict__ W,
                                               unsigned short* __restrict__ WF) {
    int b = blockIdx.x;            // o-group 0..7
    int t = threadIdx.x;
    int c2 = t & 15;               // o%16
    int fc = t >> 4;               // f-chunk 0..15
    us8 u;
    #pragma unroll
    for (int e = 0; e < 8; ++e)
        u[e] = f2bf(W[(size_t)(fc * 8 + e) * FQ + b * 16 + c2]);
    *(us8*)(WF + b * 2048 + fc * 128 + c2 * 8) = u;
}

// ---- Kernel 1: row L2-normalize x (f32) -> xnF (16 rows/block), iter 0 only ----
__global__ __launch_bounds__(256) void k_rownorm(const float* __restrict__ h,
                                                 unsigned short* __restrict__ xnF) {
    int t = threadIdx.x;
    int rl = t >> 4, j = t & 15;
    size_t row = (size_t)blockIdx.x * 16 + rl;
    const float* hr = h + row * FQ + j * 8;
    float v[8];
    #pragma unroll
    for (int e = 0; e < 8; ++e) v[e] = hr[e];
    float s = 0.f;
    #pragma unroll
    for (int e = 0; e < 8; ++e) s += v[e] * v[e];
    s += __shfl_xor(s, 1, 64);
    s += __shfl_xor(s, 2, 64);
    s += __shfl_xor(s, 4, 64);
    s += __shfl_xor(s, 8, 64);
    float inv = 1.0f / fmaxf(sqrtf(s), 1e-8f);
    us8 u;
    #pragma unroll
    for (int e = 0; e < 8; ++e) u[e] = f2bf(v[e] * inv);
    *(us8*)(xnF + (size_t)blockIdx.x * 2048 + j * 128 + rl * 8) = u;
}

// ---- Kernel 2 (r18): triangle S-tiles. Grid = 8 batches x 136 (I<=J) pairs. ----
__global__ __launch_bounds__(512) void k_adj(const unsigned short* __restrict__ xnF,
                                             unsigned char* __restrict__ adjF,
                                             float* __restrict__ dpart, float t) {
    __shared__ unsigned short As[16384];                 // 32 KB: I panel
    __shared__ union { unsigned short Bsh[16384];        // 32 KB: J panel ...
                       unsigned char  T2[128 * 132]; } ub;  // ... reused as bounce
    __shared__ float dsm[2][128];
    __shared__ float csm[2][128];

    int bid = blockIdx.x;
    int bb = bid & 7;                       // batch -> XCD locality
    int pr = bid >> 3;                      // pair index 0..135
    int I = 0;
    { int p = pr; while (p >= 16 - I) { p -= 16 - I; ++I; } pr = p; }
    int J = I + pr;

    int tid = threadIdx.x;
    int wid = tid >> 6, lane = tid & 63;
    int wr = wid >> 1, wc = wid & 1;        // 4 row-quarters x 2 col-halves
    int g = lane >> 4, c = lane & 15;

    const unsigned short* xb = xnF + (size_t)bb * NQ * FQ;
    int rowb = I * 128 + wr * 32;
    int colb = J * 128 + wc * 64;

    {   // stage panels (32 KB each, contiguous in xnF fragment layout)
        const unsigned short* srcA = xb + (size_t)(I * 8) * 2048;
        const unsigned short* srcB = xb + (size_t)(J * 8) * 2048;
        #pragma unroll
        for (int it = 0; it < 4; ++it) {
            __builtin_amdgcn_global_load_lds(
                (const __attribute__((address_space(1))) void*)(srcA + (size_t)(it * 512 + tid) * 8),
                (__attribute__((address_space(3))) void*)(As + (it * 512 + wid * 64) * 8),
                16, 0, 0);
            __builtin_amdgcn_global_load_lds(
                (const __attribute__((address_space(1))) void*)(srcB + (size_t)(it * 512 + tid) * 8),
                (__attribute__((address_space(3))) void*)(ub.Bsh + (it * 512 + wid * 64) * 8),
                16, 0, 0);
        }
    }
    __syncthreads();

    short8 a[2][4];
    #pragma unroll
    for (int mi = 0; mi < 2; ++mi)
        #pragma unroll
        for (int ks = 0; ks < 4; ++ks)
            a[mi][ks] = *(const short8*)(As + (wr * 2 + mi) * 2048 + (ks * 4 + g) * 128 + c * 8);

    f32x4 acc[2][4];
    #pragma unroll
    for (int mi = 0; mi < 2; ++mi)
        #pragma unroll
        for (int ni = 0; ni < 4; ++ni) acc[mi][ni] = (f32x4){0.f, 0.f, 0.f, 0.f};

    #pragma unroll
    for (int ni = 0; ni < 4; ++ni) {
        short8 b[4];
        #pragma unroll
        for (int ks = 0; ks < 4; ++ks)
            b[ks] = *(const short8*)(ub.Bsh + (wc * 4 + ni) * 2048 + (ks * 4 + g) * 128 + c * 8);
        #pragma unroll
        for (int mi = 0; mi < 2; ++mi)
            #pragma unroll
            for (int ks = 0; ks < 4; ++ks)
                acc[mi][ni] = __builtin_amdgcn_mfma_f32_16x16x32_bf16(a[mi][ks], b[ks], acc[mi][ni], 0, 0, 0);
    }

    __syncthreads();    // all Bsh reads done before T2 overlay writes

    unsigned char* adjb = adjF + (size_t)bb * NQ * NQ;
    float dl[2][4];
    float csl[4] = {0.f, 0.f, 0.f, 0.f};
    #pragma unroll
    for (int mi = 0; mi < 2; ++mi)
        #pragma unroll
        for (int r = 0; r < 4; ++r) dl[mi][r] = 0.f;

    #pragma unroll
    for (int mi = 0; mi < 2; ++mi)
        #pragma unroll
        for (int ni = 0; ni < 4; ++ni) {
            f32x4 v = acc[mi][ni];
            float x0 = (v[0] > t) ? v[0] : 0.0f;   // strict threshold in f32
            float x1 = (v[1] > t) ? v[1] : 0.0f;
            float x2 = (v[2] > t) ? v[2] : 0.0f;
            float x3 = (v[3] > t) ? v[3] : 0.0f;
            dl[mi][0] += x0; dl[mi][1] += x1; dl[mi][2] += x2; dl[mi][3] += x3;
            csl[ni] += x0 + x1 + x2 + x3;          // col partial (rows of this lane)
            unsigned int u = pk8lo(x0, x1, 0u);
            u = pk8hi(x2, x3, u);
            // store 1: mirror-transposed (n = col in J-range, m = row in I-range)
            *(unsigned int*)(adjb + (size_t)((colb >> 4) + ni) * NG
                                  + (size_t)((rowb >> 3) + mi * 2 + (g >> 1)) * 128
                                  + c * 8 + (g & 1) * 4) = u;
            // bounce for store 2 (skip on diagonal): T2[colL][rowL], stride 132
            if (I != J) {
                int colL = wc * 64 + ni * 16 + c;
                int rowL = wr * 32 + mi * 16 + g * 4;
                *(unsigned int*)(ub.T2 + colL * 132 + rowL) = u;
            }
        }

    // row sums -> dsm (reduce over c-lanes)
    #pragma unroll
    for (int mi = 0; mi < 2; ++mi)
        #pragma unroll
        for (int r = 0; r < 4; ++r) {
            float s = dl[mi][r];
            s += __shfl_xor(s, 1, 64);
            s += __shfl_xor(s, 2, 64);
            s += __shfl_xor(s, 4, 64);
            s += __shfl_xor(s, 8, 64);
            dl[mi][r] = s;
        }
    if (c == 0) {
        #pragma unroll
        for (int mi = 0; mi < 2; ++mi)
            #pragma unroll
            for (int r = 0; r < 4; ++r)
                dsm[wc][wr * 32 + mi * 16 + g * 4 + r] = dl[mi][r];
    }
    // col sums -> csm (reduce over g-lanes)
    if (I != J) {
        #pragma unroll
        for (int ni = 0; ni < 4; ++ni) {
            float s = csl[ni];
            s += __shfl_xor(s, 16, 64);
            s += __shfl_xor(s, 32, 64);
            csl[ni] = s;
        }
        if (lane < 16) {
            #pragma unroll
            for (int ni = 0; ni < 4; ++ni)
                csm[wr & 1][wc * 64 + ni * 16 + lane] = csl[ni];
        }
    }
    __syncthreads();
    if (I != J && (wr >= 2) && lane < 16) {
        #pragma unroll
        for (int ni = 0; ni < 4; ++ni)
            csm[wr & 1][wc * 64 + ni * 16 + lane] += csl[ni];
    }
    __syncthreads();

    // dpart writes
    if (tid < 128)
        dpart[((size_t)J * 8 + bb) * NQ + I * 128 + tid] = dsm[0][tid] + dsm[1][tid];
    if (I != J) {
        if (tid < 128)
            dpart[((size_t)I * 8 + bb) * NQ + J * 128 + tid] = csm[0][tid] + csm[1][tid];
        // store 2: direct orientation (n = row in I-range, m = col in J-range)
        int ng = wid;                 // 0..7 n-group within I-range
        int mg = lane >> 2;           // 0..15 m-group within J-range
        int part = lane & 3;          // n%16 quarter
        unsigned int w[8];
        #pragma unroll
        for (int ml = 0; ml < 8; ++ml)
            w[ml] = *(const unsigned int*)(ub.T2 + (mg * 8 + ml) * 132 + ng * 16 + part * 4);
        unsigned int o32[8];
        #pragma unroll
        for (int i = 0; i < 4; ++i)
            #pragma unroll
            for (int h = 0; h < 2; ++h)
                o32[i * 2 + h] = ((w[h * 4 + 0] >> (8 * i)) & 0xFFu)
                               | (((w[h * 4 + 1] >> (8 * i)) & 0xFFu) << 8)
                               | (((w[h * 4 + 2] >> (8 * i)) & 0xFFu) << 16)
                               | (((w[h * 4 + 3] >> (8 * i)) & 0xFFu) << 24);
        unsigned char* dst = adjb + (size_t)(I * 8 + ng) * NG + (size_t)(J * 16 + mg) * 128 + part * 32;
        *(u32x4*)dst        = (u32x4){o32[0], o32[1], o32[2], o32[3]};
        *(u32x4*)(dst + 16) = (u32x4){o32[4], o32[5], o32[6], o32[7]};
    }
}

// ---- Kernel 3a (iter 0): isq from dpart; hsF (fp8, xHSS) from f32 x ----
__global__ __launch_bounds__(256) void k_prep_f32(const float* __restrict__ h,
                                                  const float* __restrict__ dpart,
                                                  float* __restrict__ isq,
                                                  unsigned char* __restrict__ hsF) {
    __shared__ float tile[32][129];
    __shared__ float iv[32];
    int r0 = blockIdx.x * 32;
    int bb = r0 >> 11;
    int m0 = r0 & (NQ - 1);
    int tid = threadIdx.x;
    if (tid < 32) {
        float s = 0.f;
        #pragma unroll
        for (int j = 0; j < 16; ++j)
            s += dpart[((size_t)j * 8 + bb) * NQ + m0 + tid];
        float v = 1.0f / sqrtf(s);
        iv[tid] = v;
        isq[r0 + tid] = v;
    }
    #pragma unroll
    for (int it = 0; it < 16; ++it) {
        int idx = tid + it * 256;
        int mi = idx >> 7, f = idx & 127;
        tile[mi][f] = h[(size_t)(r0 + mi) * FQ + f];
    }
    __syncthreads();
    unsigned char* hb = hsF + (size_t)bb * NQ * FQ;
    #pragma unroll
    for (int it = 0; it < 2; ++it) {
        int p = tid + it * 256;
        int f = p & 127, mc = p >> 7;
        float sv[8];
        #pragma unroll
        for (int e = 0; e < 8; ++e)
            sv[e] = tile[mc * 8 + e][f] * iv[mc * 8 + e] * HSS;
        u32x2 u;
        u[0] = pk8hi(sv[2], sv[3], pk8lo(sv[0], sv[1], 0u));
        u[1] = pk8hi(sv[6], sv[7], pk8lo(sv[4], sv[5], 0u));
        *(u32x2*)(hb + (size_t)((m0 >> 3) + mc) * 1024 + f * 8) = u;
    }
}

// ---- Kernel 3b (iters 1,2): isq from dpart; hsF (fp8) from bf16 h ----
__global__ __launch_bounds__(256) void k_prep_bf16(const unsigned short* __restrict__ h,
                                                   const float* __restrict__ dpart,
                                                   float* __restrict__ isq,
                                                   unsigned char* __restrict__ hsF) {
    __shared__ float tile[32][129];
    __shared__ float iv[32];
    int r0 = blockIdx.x * 32;
    int bb = r0 >> 11;
    int m0 = r0 & (NQ - 1);
    int tid = threadIdx.x;
    if (tid < 32) {
        float s = 0.f;
        #pragma unroll
        for (int j = 0; j < 16; ++j)
            s += dpart[((size_t)j * 8 + bb) * NQ + m0 + tid];
        float v = 1.0f / sqrtf(s);
        iv[tid] = v;
        isq[r0 + tid] = v;
    }
    #pragma unroll
    for (int it = 0; it < 16; ++it) {
        int idx = tid + it * 256;
        int mi = idx >> 7, f = idx & 127;
        tile[mi][f] = bf2f(h[(size_t)(r0 + mi) * FQ + f]);
    }
    __syncthreads();
    unsigned char* hb = hsF + (size_t)bb * NQ * FQ;
    #pragma unroll
    for (int it = 0; it < 2; ++it) {
        int p = tid + it * 256;
        int f = p & 127, mc = p >> 7;
        float sv[8];
        #pragma unroll
        for (int e = 0; e < 8; ++e)
            sv[e] = tile[mc * 8 + e][f] * iv[mc * 8 + e] * HSS;
        u32x2 u;
        u[0] = pk8hi(sv[2], sv[3], pk8lo(sv[0], sv[1], 0u));
        u[1] = pk8hi(sv[6], sv[7], pk8lo(sv[4], sv[5], 0u));
        *(u32x2*)(hb + (size_t)((m0 >> 3) + mc) * 1024 + f * 8) = u;
    }
}

// ---- Kernel 4: h' = isq*(adjF_fp8 @ hsF_fp8)/HSS + in-block row-norm.
//      32-row blocks, grid 512 = 2 blocks/CU; 8 waves = 2 rg x 4 kh.
//      LAST: fused out = (h3 + x) @ W via MFMA against WF (r22). ----
template<bool LAST>
__global__ __launch_bounds__(512) void k_gemm3(const unsigned char* __restrict__ adjF,
                                               const unsigned char* __restrict__ hsF,
                                               const float* __restrict__ isq,
                                               unsigned short* __restrict__ hout,
                                               unsigned short* __restrict__ xnF,
                                               const unsigned short* __restrict__ WF,
                                               const float* __restrict__ x,
                                               float* __restrict__ out) {
    __shared__ unsigned char Bs[32768];        // 4 kh regions x 8 KB phase slice
    __shared__ float red[32][128];             // 16 KB f32 partial-sum buffer

    int bid = blockIdx.x;
    int lb = (bid & 7) * 64 + (bid >> 3);      // XCD swizzle (grid 512)
    int bb = lb >> 6;
    int rt = lb & 63;
    int row0g = rt * 32;
    int tid = threadIdx.x;
    int wid = tid >> 6, lane = tid & 63;
    int g = lane >> 4, c = lane & 15;
    int rg = wid >> 2, kh = wid & 3;
    int wrow = row0g + rg * 16;                // this wave's single n-group

    const unsigned char* adjr = adjF + (size_t)bb * NQ * NQ + (size_t)(wrow >> 4) * NG;
    const unsigned char* hb   = hsF + (size_t)bb * NQ * FQ;

    f32x4 acc[8];
    #pragma unroll
    for (int i = 0; i < 8; ++i) acc[i] = (f32x4){0.f, 0.f, 0.f, 0.f};

    int khr = wid >> 1;            // staging region this wave fills (2 waves/region)
    int wlo = wid & 1;

    for (int ph = 0; ph < 8; ++ph) {
        __syncthreads();           // previous phase's readers done
        {
            const unsigned char* src = hb + (size_t)(khr * 64 + ph * 8) * 1024 + wlo * 1024;
            unsigned char* dst = Bs + khr * 8192 + wlo * 1024;
            #pragma unroll
            for (int it = 0; it < 4; ++it) {
                __builtin_amdgcn_global_load_lds(
                    (const __attribute__((address_space(1))) void*)(src + it * 2048 + lane * 16),
                    (__attribute__((address_space(3))) void*)(dst + it * 2048),
                    16, 0, 0);
            }
        }
        __syncthreads();           // drains vmcnt
        #pragma unroll
        for (int kk2 = 0; kk2 < 2; ++kk2) {
            int mstep = kh * 16 + ph * 2 + kk2;     // global 32-elem K step
            long a0 = *(const long*)(adjr + (size_t)(mstep * 4 + g) * 128 + c * 8);
            #pragma unroll
            for (int ct = 0; ct < 8; ++ct) {
                long bfr = *(const long*)(Bs + kh * 8192 + kk2 * 4096 + g * 1024 + (ct * 16 + c) * 8);
                acc[ct] = __builtin_amdgcn_mfma_f32_16x16x32_fp8_fp8(a0, bfr, acc[ct], 0, 0, 0);
            }
        }
    }

    // cross-kh reduction into red (barrier-ordered, deterministic)
    __syncthreads();
    #pragma unroll
    for (int s = 0; s < 4; ++s) {
        if (kh == s) {
            #pragma unroll
            for (int ct = 0; ct < 8; ++ct)
                #pragma unroll
                for (int r = 0; r < 4; ++r) {
                    int rl = rg * 16 + g * 4 + r;
                    if (s == 0) red[rl][ct * 16 + c] = acc[ct][r];
                    else        red[rl][ct * 16 + c] += acc[ct][r];
                }
        }
        __syncthreads();
    }

    if constexpr (!LAST) {
        // scale, row-norm, write h bf16 + next-iter xnF fragments
        int rl = tid >> 4;             // 0..31
        int j  = tid & 15;             // 16 f-chunks of 8
        int n  = row0g + rl;
        float scale = isq[(size_t)bb * NQ + n] * (1.0f / HSS);
        float v[8];
        float s = 0.f;
        #pragma unroll
        for (int e = 0; e < 8; ++e) {
            float xv = red[rl][j * 8 + e] * scale;
            v[e] = xv;
            s += xv * xv;
        }
        s += __shfl_xor(s, 1, 64);
        s += __shfl_xor(s, 2, 64);
        s += __shfl_xor(s, 4, 64);
        s += __shfl_xor(s, 8, 64);
        float inv = 1.0f / fmaxf(sqrtf(s), 1e-8f);

        us8 h0;
        #pragma unroll
        for (int e = 0; e < 8; ++e) h0[e] = f2bf(v[e]);
        *(us8*)(hout + ((size_t)bb * NQ + n) * FQ + j * 8) = h0;

        us8 u0;
        #pragma unroll
        for (int e = 0; e < 8; ++e) u0[e] = f2bf(v[e] * inv);
        unsigned short* xd = xnF + (size_t)bb * NQ * FQ + (size_t)(n >> 4) * 2048
                                 + j * 128 + (n & 15) * 8;
        *(us8*)xd = u0;
    } else {
        // fused epilogue: out = (h3 + x) @ W, MFMA bf16 against WF
        unsigned short* hxs = (unsigned short*)Bs;    // 8 KB reuse (staging done)
        {
            int rl = tid >> 4, j = tid & 15;
            int n = row0g + rl;
            float scale = isq[(size_t)bb * NQ + n] * (1.0f / HSS);
            const float* xr = x + ((size_t)bb * NQ + n) * FQ + j * 8;
            us8 hxv;
            #pragma unroll
            for (int e = 0; e < 8; ++e)
                hxv[e] = f2bf(red[rl][j * 8 + e] * scale + xr[e]);
            int wb = (rl * 256 + j * 16) ^ ((rl & 7) << 4);   // XOR swizzle (G4)
            *(us8*)((char*)hxs + wb) = hxv;
        }
        __syncthreads();
        {
            int rg2 = wid >> 2, oq = wid & 3;      // 2 row-halves x 4 o-quarters
            f32x4 oacc[2];
            oacc[0] = (f32x4){0.f, 0.f, 0.f, 0.f};
            oacc[1] = (f32x4){0.f, 0.f, 0.f, 0.f};
            int row = rg2 * 16 + c;
            #pragma unroll
            for (int ks = 0; ks < 4; ++ks) {
                short8 af = *(const short8*)((const char*)hxs
                              + ((row * 256 + ks * 64 + g * 16) ^ ((row & 7) << 4)));
                #pragma unroll
                for (int ct = 0; ct < 2; ++ct) {
                    int og = oq * 2 + ct;
                    short8 bf = *(const short8*)(WF + og * 2048 + (ks * 4 + g) * 128 + c * 8);
                    oacc[ct] = __builtin_amdgcn_mfma_f32_16x16x32_bf16(af, bf, oacc[ct], 0, 0, 0);
                }
            }
            float* ob = out + ((size_t)bb * NQ + row0g) * FQ;
            #pragma unroll
            for (int ct = 0; ct < 2; ++ct)
                #pragma unroll
                for (int r = 0; r < 4; ++r)
                    ob[(size_t)(rg2 * 16 + g * 4 + r) * FQ + oq * 32 + ct * 16 + c] = oacc[ct][r];
        }
    }
}

extern "C" void kernel_launch(void* const* d_in, const int* in_sizes, int n_in,
                              void* d_out, int out_size, void* d_ws, size_t ws_size,
                              hipStream_t stream) {
    const float* x = (const float*)d_in[0];
    const float* W = (const float*)d_in[1];
    float* out = (float*)d_out;
    char* ws = (char*)d_ws;

    const size_t CS   = (size_t)BQ * NQ * FQ;
    const size_t oADJ = 0;
    const size_t oXN  = oADJ + (size_t)BQ * NQ * NQ;          // 32 MiB fp8 adj
    const size_t oHST = oXN  + CS * 2;                        // +4 MiB bf16 xn
    const size_t oD   = oHST + CS;                            // +2 MiB fp8 hs
    const size_t oISQ = oD   + (size_t)16 * BQ * NQ * 4;      // +1 MiB
    const size_t oHA  = oISQ + (size_t)BQ * NQ * 4;           // +64 KiB
    const size_t oHB  = oHA  + CS * 2;                        // +4 MiB bf16 hA
    const size_t oWF  = oHB  + CS * 2;                        // +4 MiB bf16 hB
    const size_t need = oWF  + (size_t)FQ * FQ * 2;           // +32 KiB WF
    if (ws_size < need) return;   // diagnostic: output stays poisoned

    unsigned char*  adjF = (unsigned char*)(ws + oADJ);
    unsigned short* xnF  = (unsigned short*)(ws + oXN);
    unsigned char*  hsF  = (unsigned char*)(ws + oHST);
    float* dpart = (float*)(ws + oD);
    float* isq   = (float*)(ws + oISQ);
    unsigned short* hA = (unsigned short*)(ws + oHA);
    unsigned short* hB = (unsigned short*)(ws + oHB);
    unsigned short* WF = (unsigned short*)(ws + oWF);

    const float ts[3] = {0.05f, 0.1f, 0.15f};

    k_wprep<<<8, 256, 0, stream>>>(W, WF);

    // iter 0
    k_rownorm<<<BQ * NQ / 16, 256, 0, stream>>>(x, xnF);
    k_adj<<<BQ * 136, 512, 0, stream>>>(xnF, adjF, dpart, ts[0]);
    k_prep_f32<<<BQ * NQ / 32, 256, 0, stream>>>(x, dpart, isq, hsF);
    k_gemm3<false><<<BQ * 64, 512, 0, stream>>>(adjF, hsF, isq, hA, xnF, WF, x, out);
    // iter 1
    k_adj<<<BQ * 136, 512, 0, stream>>>(xnF, adjF, dpart, ts[1]);
    k_prep_bf16<<<BQ * NQ / 32, 256, 0, stream>>>(hA, dpart, isq, hsF);
    k_gemm3<false><<<BQ * 64, 512, 0, stream>>>(adjF, hsF, isq, hB, xnF, WF, x, out);
    // iter 2
    k_adj<<<BQ * 136, 512, 0, stream>>>(xnF, adjF, dpart, ts[2]);
    k_prep_bf16<<<BQ * NQ / 32, 256, 0, stream>>>(hB, dpart, isq, hsF);
    k_gemm3<true><<<BQ * 64, 512, 0, stream>>>(adjF, hsF, isq, hA, xnF, WF, x, out);
}

// Round 23
// 116.884 us; speedup vs baseline: 11.0784x; 1.0512x over previous
//
#include <hip/hip_runtime.h>
#include <hip/hip_bf16.h>
#include <cstdint>

#define BQ 8
#define NQ 2048
#define FQ 128
#define NG (NQ * 16)            // adjF n-group stride in BYTES (fp8)
#define HSS 256.0f              // hs fp8 scale

typedef __attribute__((ext_vector_type(8))) short short8;
typedef __attribute__((ext_vector_type(4))) float f32x4;
typedef __attribute__((ext_vector_type(8))) unsigned short us8;
typedef __attribute__((ext_vector_type(2))) unsigned int u32x2;
typedef __attribute__((ext_vector_type(4))) unsigned int u32x4;

__device__ __forceinline__ unsigned short f2bf(float f) {
    union { float f; unsigned int u; } c; c.f = f;
    unsigned int u = c.u;
    u = (u + 0x7FFFu + ((u >> 16) & 1u)) >> 16;   // RNE
    return (unsigned short)u;
}
__device__ __forceinline__ float bf2f(unsigned short u) {
    union { unsigned int i; float f; } c; c.i = (unsigned int)u << 16; return c.f;
}
__device__ __forceinline__ unsigned int pk8lo(float a, float b, unsigned int old) {
    return (unsigned int)__builtin_amdgcn_cvt_pk_fp8_f32(a, b, (int)old, false);
}
__device__ __forceinline__ unsigned int pk8hi(float a, float b, unsigned int old) {
    return (unsigned int)__builtin_amdgcn_cvt_pk_fp8_f32(a, b, (int)old, true);
}

// Layouts (per batch):
//   xnF : bf16 [n/16][k/8][n%16][k%8]  elem addr = (n>>4)*2048 + (k>>3)*128 + (n&15)*8 + (k&7)
//   adjF: fp8  [n/16][m/8][n%16][m%8]  BYTE addr = (n>>4)*NG + (m>>3)*128 + (n&15)*8 + (m&7)
//   hsF : fp8  [m/8][f][m%8]           BYTE addr = (m>>3)*1024 + f*8 + (m&7); value = hs*HSS
//   WF  : bf16 [o/16][f/8][o%16][f%8]  (W fragment layout, B-operand)
// h buffers: bf16 row-major [b][n][f].
// r23: gemm3 double-buffered staging (1 barrier/phase, red aliases dead buf0);
// prep reads h direct (no LDS tile); wprep merged into rownorm launch.

// ---- Kernel 1: blocks 0-7 = WF prep; blocks 8+ = row L2-normalize x -> xnF ----
__global__ __launch_bounds__(256) void k_rownorm(const float* __restrict__ h,
                                                 unsigned short* __restrict__ xnF,
                                                 const float* __restrict__ W,
                                                 unsigned short* __restrict__ WF) {
    int t = threadIdx.x;
    if (blockIdx.x < 8) {          // WF[o/16][f/8][o%16][f%8] = bf16(W[f][o])
        int b = blockIdx.x;
        int c2 = t & 15, fc = t >> 4;
        us8 u;
        #pragma unroll
        for (int e = 0; e < 8; ++e)
            u[e] = f2bf(W[(size_t)(fc * 8 + e) * FQ + b * 16 + c2]);
        *(us8*)(WF + b * 2048 + fc * 128 + c2 * 8) = u;
        return;
    }
    int bid = blockIdx.x - 8;
    int rl = t >> 4, j = t & 15;
    size_t row = (size_t)bid * 16 + rl;
    const float* hr = h + row * FQ + j * 8;
    float v[8];
    #pragma unroll
    for (int e = 0; e < 8; ++e) v[e] = hr[e];
    float s = 0.f;
    #pragma unroll
    for (int e = 0; e < 8; ++e) s += v[e] * v[e];
    s += __shfl_xor(s, 1, 64);
    s += __shfl_xor(s, 2, 64);
    s += __shfl_xor(s, 4, 64);
    s += __shfl_xor(s, 8, 64);
    float inv = 1.0f / fmaxf(sqrtf(s), 1e-8f);
    us8 u;
    #pragma unroll
    for (int e = 0; e < 8; ++e) u[e] = f2bf(v[e] * inv);
    *(us8*)(xnF + (size_t)bid * 2048 + j * 128 + rl * 8) = u;
}

// ---- Kernel 2 (r18, unchanged): triangle S-tiles. Grid = 8 x 136 pairs. ----
__global__ __launch_bounds__(512) void k_adj(const unsigned short* __restrict__ xnF,
                                             unsigned char* __restrict__ adjF,
                                             float* __restrict__ dpart, float t) {
    __shared__ unsigned short As[16384];
    __shared__ union { unsigned short Bsh[16384];
                       unsigned char  T2[128 * 132]; } ub;
    __shared__ float dsm[2][128];
    __shared__ float csm[2][128];

    int bid = blockIdx.x;
    int bb = bid & 7;
    int pr = bid >> 3;
    int I = 0;
    { int p = pr; while (p >= 16 - I) { p -= 16 - I; ++I; } pr = p; }
    int J = I + pr;

    int tid = threadIdx.x;
    int wid = tid >> 6, lane = tid & 63;
    int wr = wid >> 1, wc = wid & 1;
    int g = lane >> 4, c = lane & 15;

    const unsigned short* xb = xnF + (size_t)bb * NQ * FQ;
    int rowb = I * 128 + wr * 32;
    int colb = J * 128 + wc * 64;

    {
        const unsigned short* srcA = xb + (size_t)(I * 8) * 2048;
        const unsigned short* srcB = xb + (size_t)(J * 8) * 2048;
        #pragma unroll
        for (int it = 0; it < 4; ++it) {
            __builtin_amdgcn_global_load_lds(
                (const __attribute__((address_space(1))) void*)(srcA + (size_t)(it * 512 + tid) * 8),
                (__attribute__((address_space(3))) void*)(As + (it * 512 + wid * 64) * 8),
                16, 0, 0);
            __builtin_amdgcn_global_load_lds(
                (const __attribute__((address_space(1))) void*)(srcB + (size_t)(it * 512 + tid) * 8),
                (__attribute__((address_space(3))) void*)(ub.Bsh + (it * 512 + wid * 64) * 8),
                16, 0, 0);
        }
    }
    __syncthreads();

    short8 a[2][4];
    #pragma unroll
    for (int mi = 0; mi < 2; ++mi)
        #pragma unroll
        for (int ks = 0; ks < 4; ++ks)
            a[mi][ks] = *(const short8*)(As + (wr * 2 + mi) * 2048 + (ks * 4 + g) * 128 + c * 8);

    f32x4 acc[2][4];
    #pragma unroll
    for (int mi = 0; mi < 2; ++mi)
        #pragma unroll
        for (int ni = 0; ni < 4; ++ni) acc[mi][ni] = (f32x4){0.f, 0.f, 0.f, 0.f};

    #pragma unroll
    for (int ni = 0; ni < 4; ++ni) {
        short8 b[4];
        #pragma unroll
        for (int ks = 0; ks < 4; ++ks)
            b[ks] = *(const short8*)(ub.Bsh + (wc * 4 + ni) * 2048 + (ks * 4 + g) * 128 + c * 8);
        #pragma unroll
        for (int mi = 0; mi < 2; ++mi)
            #pragma unroll
            for (int ks = 0; ks < 4; ++ks)
                acc[mi][ni] = __builtin_amdgcn_mfma_f32_16x16x32_bf16(a[mi][ks], b[ks], acc[mi][ni], 0, 0, 0);
    }

    __syncthreads();

    unsigned char* adjb = adjF + (size_t)bb * NQ * NQ;
    float dl[2][4];
    float csl[4] = {0.f, 0.f, 0.f, 0.f};
    #pragma unroll
    for (int mi = 0; mi < 2; ++mi)
        #pragma unroll
        for (int r = 0; r < 4; ++r) dl[mi][r] = 0.f;

    #pragma unroll
    for (int mi = 0; mi < 2; ++mi)
        #pragma unroll
        for (int ni = 0; ni < 4; ++ni) {
            f32x4 v = acc[mi][ni];
            float x0 = (v[0] > t) ? v[0] : 0.0f;
            float x1 = (v[1] > t) ? v[1] : 0.0f;
            float x2 = (v[2] > t) ? v[2] : 0.0f;
            float x3 = (v[3] > t) ? v[3] : 0.0f;
            dl[mi][0] += x0; dl[mi][1] += x1; dl[mi][2] += x2; dl[mi][3] += x3;
            csl[ni] += x0 + x1 + x2 + x3;
            unsigned int u = pk8lo(x0, x1, 0u);
            u = pk8hi(x2, x3, u);
            *(unsigned int*)(adjb + (size_t)((colb >> 4) + ni) * NG
                                  + (size_t)((rowb >> 3) + mi * 2 + (g >> 1)) * 128
                                  + c * 8 + (g & 1) * 4) = u;
            if (I != J) {
                int colL = wc * 64 + ni * 16 + c;
                int rowL = wr * 32 + mi * 16 + g * 4;
                *(unsigned int*)(ub.T2 + colL * 132 + rowL) = u;
            }
        }

    #pragma unroll
    for (int mi = 0; mi < 2; ++mi)
        #pragma unroll
        for (int r = 0; r < 4; ++r) {
            float s = dl[mi][r];
            s += __shfl_xor(s, 1, 64);
            s += __shfl_xor(s, 2, 64);
            s += __shfl_xor(s, 4, 64);
            s += __shfl_xor(s, 8, 64);
            dl[mi][r] = s;
        }
    if (c == 0) {
        #pragma unroll
        for (int mi = 0; mi < 2; ++mi)
            #pragma unroll
            for (int r = 0; r < 4; ++r)
                dsm[wc][wr * 32 + mi * 16 + g * 4 + r] = dl[mi][r];
    }
    if (I != J) {
        #pragma unroll
        for (int ni = 0; ni < 4; ++ni) {
            float s = csl[ni];
            s += __shfl_xor(s, 16, 64);
            s += __shfl_xor(s, 32, 64);
            csl[ni] = s;
        }
        if (lane < 16) {
            #pragma unroll
            for (int ni = 0; ni < 4; ++ni)
                csm[wr & 1][wc * 64 + ni * 16 + lane] = csl[ni];
        }
    }
    __syncthreads();
    if (I != J && (wr >= 2) && lane < 16) {
        #pragma unroll
        for (int ni = 0; ni < 4; ++ni)
            csm[wr & 1][wc * 64 + ni * 16 + lane] += csl[ni];
    }
    __syncthreads();

    if (tid < 128)
        dpart[((size_t)J * 8 + bb) * NQ + I * 128 + tid] = dsm[0][tid] + dsm[1][tid];
    if (I != J) {
        if (tid < 128)
            dpart[((size_t)I * 8 + bb) * NQ + J * 128 + tid] = csm[0][tid] + csm[1][tid];
        int ng = wid;
        int mg = lane >> 2;
        int part = lane & 3;
        unsigned int w[8];
        #pragma unroll
        for (int ml = 0; ml < 8; ++ml)
            w[ml] = *(const unsigned int*)(ub.T2 + (mg * 8 + ml) * 132 + ng * 16 + part * 4);
        unsigned int o32[8];
        #pragma unroll
        for (int i = 0; i < 4; ++i)
            #pragma unroll
            for (int h = 0; h < 2; ++h)
                o32[i * 2 + h] = ((w[h * 4 + 0] >> (8 * i)) & 0xFFu)
                               | (((w[h * 4 + 1] >> (8 * i)) & 0xFFu) << 8)
                               | (((w[h * 4 + 2] >> (8 * i)) & 0xFFu) << 16)
                               | (((w[h * 4 + 3] >> (8 * i)) & 0xFFu) << 24);
        unsigned char* dst = adjb + (size_t)(I * 8 + ng) * NG + (size_t)(J * 16 + mg) * 128 + part * 32;
        *(u32x4*)dst        = (u32x4){o32[0], o32[1], o32[2], o32[3]};
        *(u32x4*)(dst + 16) = (u32x4){o32[4], o32[5], o32[6], o32[7]};
    }
}

// ---- Kernel 3a (iter 0): isq from dpart; hsF (fp8, xHSS) from f32 x (direct) ----
__global__ __launch_bounds__(256) void k_prep_f32(const float* __restrict__ h,
                                                  const float* __restrict__ dpart,
                                                  float* __restrict__ isq,
                                                  unsigned char* __restrict__ hsF) {
    __shared__ float iv[32];
    int r0 = blockIdx.x * 32;
    int bb = r0 >> 11;
    int m0 = r0 & (NQ - 1);
    int tid = threadIdx.x;
    if (tid < 32) {
        float s = 0.f;
        #pragma unroll
        for (int j = 0; j < 16; ++j)
            s += dpart[((size_t)j * 8 + bb) * NQ + m0 + tid];
        float v = 1.0f / sqrtf(s);
        iv[tid] = v;
        isq[r0 + tid] = v;
    }
    __syncthreads();
    unsigned char* hb = hsF + (size_t)bb * NQ * FQ;
    #pragma unroll
    for (int it = 0; it < 2; ++it) {
        int p = tid + it * 256;
        int f = p & 127, mc = p >> 7;          // mc 0..3
        float sv[8];
        #pragma unroll
        for (int e = 0; e < 8; ++e)
            sv[e] = h[(size_t)(r0 + mc * 8 + e) * FQ + f] * iv[mc * 8 + e] * HSS;
        u32x2 u;
        u[0] = pk8hi(sv[2], sv[3], pk8lo(sv[0], sv[1], 0u));
        u[1] = pk8hi(sv[6], sv[7], pk8lo(sv[4], sv[5], 0u));
        *(u32x2*)(hb + (size_t)((m0 >> 3) + mc) * 1024 + f * 8) = u;
    }
}

// ---- Kernel 3b (iters 1,2): isq from dpart; hsF (fp8) from bf16 h (direct) ----
__global__ __launch_bounds__(256) void k_prep_bf16(const unsigned short* __restrict__ h,
                                                   const float* __restrict__ dpart,
                                                   float* __restrict__ isq,
                                                   unsigned char* __restrict__ hsF) {
    __shared__ float iv[32];
    int r0 = blockIdx.x * 32;
    int bb = r0 >> 11;
    int m0 = r0 & (NQ - 1);
    int tid = threadIdx.x;
    if (tid < 32) {
        float s = 0.f;
        #pragma unroll
        for (int j = 0; j < 16; ++j)
            s += dpart[((size_t)j * 8 + bb) * NQ + m0 + tid];
        float v = 1.0f / sqrtf(s);
        iv[tid] = v;
        isq[r0 + tid] = v;
    }
    __syncthreads();
    unsigned char* hb = hsF + (size_t)bb * NQ * FQ;
    #pragma unroll
    for (int it = 0; it < 2; ++it) {
        int p = tid + it * 256;
        int f = p & 127, mc = p >> 7;
        float sv[8];
        #pragma unroll
        for (int e = 0; e < 8; ++e)
            sv[e] = bf2f(h[(size_t)(r0 + mc * 8 + e) * FQ + f]) * iv[mc * 8 + e] * HSS;
        u32x2 u;
        u[0] = pk8hi(sv[2], sv[3], pk8lo(sv[0], sv[1], 0u));
        u[1] = pk8hi(sv[6], sv[7], pk8lo(sv[4], sv[5], 0u));
        *(u32x2*)(hb + (size_t)((m0 >> 3) + mc) * 1024 + f * 8) = u;
    }
}

// ---- Kernel 4 (r23): gemm3 with double-buffered staging (1 barrier/phase).
//      32-row blocks, grid 512 = 2 blocks/CU; red aliases dead buf0. ----
template<bool LAST>
__global__ __launch_bounds__(512) void k_gemm3(const unsigned char* __restrict__ adjF,
                                               const unsigned char* __restrict__ hsF,
                                               const float* __restrict__ isq,
                                               unsigned short* __restrict__ hout,
                                               unsigned short* __restrict__ xnF,
                                               const unsigned short* __restrict__ WF,
                                               const float* __restrict__ x,
                                               float* __restrict__ out) {
    __shared__ unsigned char BsD[2][32768];    // double-buffered stage (64 KB)
    float (*red)[128] = (float (*)[128])(&BsD[0][0]);   // alias: buf0 dead after loop

    int bid = blockIdx.x;
    int lb = (bid & 7) * 64 + (bid >> 3);      // XCD swizzle (grid 512)
    int bb = lb >> 6;
    int rt = lb & 63;
    int row0g = rt * 32;
    int tid = threadIdx.x;
    int wid = tid >> 6, lane = tid & 63;
    int g = lane >> 4, c = lane & 15;
    int rg = wid >> 2, kh = wid & 3;
    int wrow = row0g + rg * 16;

    const unsigned char* adjr = adjF + (size_t)bb * NQ * NQ + (size_t)(wrow >> 4) * NG;
    const unsigned char* hb   = hsF + (size_t)bb * NQ * FQ;

    f32x4 acc[8];
    #pragma unroll
    for (int i = 0; i < 8; ++i) acc[i] = (f32x4){0.f, 0.f, 0.f, 0.f};

    int khr = wid >> 1;
    int wlo = wid & 1;

    #define STAGE(P, BUF)                                                           \
        {                                                                           \
            const unsigned char* src_ = hb + (size_t)(khr * 64 + (P) * 8) * 1024 + wlo * 1024; \
            unsigned char* dst_ = (BUF) + khr * 8192 + wlo * 1024;                  \
            _Pragma("unroll")                                                       \
            for (int it_ = 0; it_ < 4; ++it_) {                                     \
                __builtin_amdgcn_global_load_lds(                                   \
                    (const __attribute__((address_space(1))) void*)(src_ + it_ * 2048 + lane * 16), \
                    (__attribute__((address_space(3))) void*)(dst_ + it_ * 2048),   \
                    16, 0, 0);                                                      \
            }                                                                       \
        }

    STAGE(0, BsD[0]);
    __syncthreads();               // buf0 ready (compiler drains vmcnt)
    for (int ph = 0; ph < 8; ++ph) {
        if (ph < 7) STAGE(ph + 1, BsD[(ph + 1) & 1]);   // hides under compute
        const unsigned char* cur = BsD[ph & 1];
        #pragma unroll
        for (int kk2 = 0; kk2 < 2; ++kk2) {
            int mstep = kh * 16 + ph * 2 + kk2;
            long a0 = *(const long*)(adjr + (size_t)(mstep * 4 + g) * 128 + c * 8);
            #pragma unroll
            for (int ct = 0; ct < 8; ++ct) {
                long bfr = *(const long*)(cur + kh * 8192 + kk2 * 4096 + g * 1024 + (ct * 16 + c) * 8);
                acc[ct] = __builtin_amdgcn_mfma_f32_16x16x32_fp8_fp8(a0, bfr, acc[ct], 0, 0, 0);
            }
        }
        __syncthreads();           // drains next stage; protects buf reuse
    }
    #undef STAGE

    // cross-kh reduction into red (aliases buf0; all buf0 reads behind barriers)
    #pragma unroll
    for (int s = 0; s < 4; ++s) {
        if (kh == s) {
            #pragma unroll
            for (int ct = 0; ct < 8; ++ct)
                #pragma unroll
                for (int r = 0; r < 4; ++r) {
                    int rl = rg * 16 + g * 4 + r;
                    if (s == 0) red[rl][ct * 16 + c] = acc[ct][r];
                    else        red[rl][ct * 16 + c] += acc[ct][r];
                }
        }
        __syncthreads();
    }

    if constexpr (!LAST) {
        int rl = tid >> 4;
        int j  = tid & 15;
        int n  = row0g + rl;
        float scale = isq[(size_t)bb * NQ + n] * (1.0f / HSS);
        float v[8];
        float s = 0.f;
        #pragma unroll
        for (int e = 0; e < 8; ++e) {
            float xv = red[rl][j * 8 + e] * scale;
            v[e] = xv;
            s += xv * xv;
        }
        s += __shfl_xor(s, 1, 64);
        s += __shfl_xor(s, 2, 64);
        s += __shfl_xor(s, 4, 64);
        s += __shfl_xor(s, 8, 64);
        float inv = 1.0f / fmaxf(sqrtf(s), 1e-8f);

        us8 h0;
        #pragma unroll
        for (int e = 0; e < 8; ++e) h0[e] = f2bf(v[e]);
        *(us8*)(hout + ((size_t)bb * NQ + n) * FQ + j * 8) = h0;

        us8 u0;
        #pragma unroll
        for (int e = 0; e < 8; ++e) u0[e] = f2bf(v[e] * inv);
        unsigned short* xd = xnF + (size_t)bb * NQ * FQ + (size_t)(n >> 4) * 2048
                                 + j * 128 + (n & 15) * 8;
        *(us8*)xd = u0;
    } else {
        // fused epilogue: out = (h3 + x) @ W, MFMA bf16 against WF
        unsigned short* hxs = (unsigned short*)(&BsD[1][0]);   // disjoint from red
        {
            int rl = tid >> 4, j = tid & 15;
            int n = row0g + rl;
            float scale = isq[(size_t)bb * NQ + n] * (1.0f / HSS);
            const float* xr = x + ((size_t)bb * NQ + n) * FQ + j * 8;
            us8 hxv;
            #pragma unroll
            for (int e = 0; e < 8; ++e)
                hxv[e] = f2bf(red[rl][j * 8 + e] * scale + xr[e]);
            int wb = (rl * 256 + j * 16) ^ ((rl & 7) << 4);   // XOR swizzle (G4)
            *(us8*)((char*)hxs + wb) = hxv;
        }
        __syncthreads();
        {
            int rg2 = wid >> 2, oq = wid & 3;
            f32x4 oacc[2];
            oacc[0] = (f32x4){0.f, 0.f, 0.f, 0.f};
            oacc[1] = (f32x4){0.f, 0.f, 0.f, 0.f};
            int row = rg2 * 16 + c;
            #pragma unroll
            for (int ks = 0; ks < 4; ++ks) {
                short8 af = *(const short8*)((const char*)hxs
                              + ((row * 256 + ks * 64 + g * 16) ^ ((row & 7) << 4)));
                #pragma unroll
                for (int ct = 0; ct < 2; ++ct) {
                    int og = oq * 2 + ct;
                    short8 bf = *(const short8*)(WF + og * 2048 + (ks * 4 + g) * 128 + c * 8);
                    oacc[ct] = __builtin_amdgcn_mfma_f32_16x16x32_bf16(af, bf, oacc[ct], 0, 0, 0);
                }
            }
            float* ob = out + ((size_t)bb * NQ + row0g) * FQ;
            #pragma unroll
            for (int ct = 0; ct < 2; ++ct)
                #pragma unroll
                for (int r = 0; r < 4; ++r)
                    ob[(size_t)(rg2 * 16 + g * 4 + r) * FQ + oq * 32 + ct * 16 + c] = oacc[ct][r];
        }
    }
}

extern "C" void kernel_launch(void* const* d_in, const int* in_sizes, int n_in,
                              void* d_out, int out_size, void* d_ws, size_t ws_size,
                              hipStream_t stream) {
    const float* x = (const float*)d_in[0];
    const float* W = (const float*)d_in[1];
    float* out = (float*)d_out;
    char* ws = (char*)d_ws;

    const size_t CS   = (size_t)BQ * NQ * FQ;
    const size_t oADJ = 0;
    const size_t oXN  = oADJ + (size_t)BQ * NQ * NQ;          // 32 MiB fp8 adj
    const size_t oHST = oXN  + CS * 2;                        // +4 MiB bf16 xn
    const size_t oD   = oHST + CS;                            // +2 MiB fp8 hs
    const size_t oISQ = oD   + (size_t)16 * BQ * NQ * 4;      // +1 MiB
    const size_t oHA  = oISQ + (size_t)BQ * NQ * 4;           // +64 KiB
    const size_t oHB  = oHA  + CS * 2;                        // +4 MiB bf16 hA
    const size_t oWF  = oHB  + CS * 2;                        // +4 MiB bf16 hB
    const size_t need = oWF  + (size_t)FQ * FQ * 2;           // +32 KiB WF
    if (ws_size < need) return;   // diagnostic: output stays poisoned

    unsigned char*  adjF = (unsigned char*)(ws + oADJ);
    unsigned short* xnF  = (unsigned short*)(ws + oXN);
    unsigned char*  hsF  = (unsigned char*)(ws + oHST);
    float* dpart = (float*)(ws + oD);
    float* isq   = (float*)(ws + oISQ);
    unsigned short* hA = (unsigned short*)(ws + oHA);
    unsigned short* hB = (unsigned short*)(ws + oHB);
    unsigned short* WF = (unsigned short*)(ws + oWF);

    const float ts[3] = {0.05f, 0.1f, 0.15f};

    // iter 0 (blocks 0-7 of k_rownorm build WF)
    k_rownorm<<<BQ * NQ / 16 + 8, 256, 0, stream>>>(x, xnF, W, WF);
    k_adj<<<BQ * 136, 512, 0, stream>>>(xnF, adjF, dpart, ts[0]);
    k_prep_f32<<<BQ * NQ / 32, 256, 0, stream>>>(x, dpart, isq, hsF);
    k_gemm3<false><<<BQ * 64, 512, 0, stream>>>(adjF, hsF, isq, hA, xnF, WF, x, out);
    // iter 1
    k_adj<<<BQ * 136, 512, 0, stream>>>(xnF, adjF, dpart, ts[1]);
    k_prep_bf16<<<BQ * NQ / 32, 256, 0, stream>>>(hA, dpart, isq, hsF);
    k_gemm3<false><<<BQ * 64, 512, 0, stream>>>(adjF, hsF, isq, hB, xnF, WF, x, out);
    // iter 2
    k_adj<<<BQ * 136, 512, 0, stream>>>(xnF, adjF, dpart, ts[2]);
    k_prep_bf16<<<BQ * NQ / 32, 256, 0, stream>>>(hB, dpart, isq, hsF);
    k_gemm3<true><<<BQ * 64, 512, 0, stream>>>(adjF, hsF, isq, hA, xnF, WF, x, out);
}